// Round 10
// baseline (294.634 us; speedup 1.0000x reference)
//
#include <hip/hip_runtime.h>
#include <math.h>

#define N_ROWS 16384
#define VOCAB  8192
#define EMB    256

// ---- MFMA path tiling ----
#define BM 128
#define BV 128
#define BK 64                      // halfs per staged K-chunk (2 MFMA k-steps)
#define VSPLIT 8                   // grid (128, 8)
#define VRANGE (VOCAB / VSPLIT)    // 1024
#define NVT    (VRANGE / BV)       // 8
#define TAU 0.15f                  // rescue margin: >= 2*max|dist err| (fp16 inputs)

typedef _Float16 half8 __attribute__((ext_vector_type(8)));
typedef _Float16 half4 __attribute__((ext_vector_type(4)));
typedef float floatx4 __attribute__((ext_vector_type(4)));

// async global->LDS DMA, 16 B/lane; LDS dest = wave-uniform base + lane*16
__device__ __forceinline__ void load_lds16(const _Float16* g, _Float16* l) {
    __builtin_amdgcn_global_load_lds(
        (const __attribute__((address_space(1))) void*)g,
        (__attribute__((address_space(3))) void*)l, 16, 0, 0);
}

// ---------------------------------------------------------------------------
// PREP (1 dispatch replaces esq + split + memsets).
// counters: flagcnt[0] = candidate-rescore count, flagcnt[1] = full-scan count
// ---------------------------------------------------------------------------
__global__ void prep_kernel(const float* __restrict__ z, const float* __restrict__ cb,
                            _Float16* __restrict__ zh, _Float16* __restrict__ ch,
                            float* __restrict__ esq, float* __restrict__ cnt,
                            unsigned long long* __restrict__ rkey,
                            int* __restrict__ flagcnt) {
    const int b = blockIdx.x, t = threadIdx.x;
    if (b < VOCAB / 4) {
        const int row  = b * 4 + (t >> 6);
        const int lane = t & 63;
        const float4 f = *(const float4*)(cb + (size_t)row * EMB + lane * 4);
        half4 h;
        h.x = (_Float16)f.x; h.y = (_Float16)f.y; h.z = (_Float16)f.z; h.w = (_Float16)f.w;
        *(half4*)(ch + (size_t)row * EMB + lane * 4) = h;
        float s = f.x * f.x + f.y * f.y + f.z * f.z + f.w * f.w;
        #pragma unroll
        for (int off = 32; off > 0; off >>= 1) s += __shfl_down(s, off, 64);
        if (lane == 0) esq[row] = s;
        if (t < 4) cnt[b * 4 + t] = 0.0f;
        if (t >= 8 && t < 16) rkey[b * 8 + (t - 8)] = ~0ull;
        if (b == 0 && t == 4) flagcnt[0] = 0;
        if (b == 0 && t == 5) flagcnt[1] = 0;
    } else {
        const size_t idx4 = (size_t)(b - VOCAB / 4) * 256 + t;
        const float4 f = *(const float4*)(z + idx4 * 4);
        half4 h;
        h.x = (_Float16)f.x; h.y = (_Float16)f.y; h.z = (_Float16)f.z; h.w = (_Float16)f.w;
        *(half4*)(zh + idx4 * 4) = h;
    }
}

// ---------------------------------------------------------------------------
// MFMA dist kernel v16: v14 (dual V-tile, 114.6us proven) + it-boundary
// stage prefetch. r9 post-mortem: v15 single-sync dbuf REGRESSED (122us) —
// one step's MFMA (~100cy) can't cover ~500cy DMA latency; v14's fewer/
// bigger drains win. v16 keeps v14 verbatim except: the stage of (it+1,kt0)
// is issued BEFORE the tracking block (buffers free after kt3's trailing
// barrier) — the ~224 wave-ops (~450cy) of tracking VALU cover the DMA, so
// kt0's drain finds it complete. Hides 4 of 16 drains/block at zero cost.
// Tracking: r7 mantissa-embedded codes; codes (it<<3)|(tb<<2)|j.
// ---------------------------------------------------------------------------
#define KSTEP(KO, DOSTAGE)                                                     \
    {                                                                          \
        if (DOSTAGE) {                                                         \
            _Pragma("unroll")                                                  \
            for (int q = 0; q < 4; ++q) {                                      \
                load_lds16(zsrc  + (size_t)q * 8 * EMB + (KO),                 \
                           &zs [w * 2048 + q * 512]);                          \
                load_lds16(csrcA + (size_t)q * 8 * EMB + (KO),                 \
                           &csA[w * 2048 + q * 512]);                          \
                load_lds16(csrcB + (size_t)q * 8 * EMB + (KO),                 \
                           &csB[w * 2048 + q * 512]);                          \
            }                                                                  \
        }                                                                      \
        __syncthreads();                                                       \
        _Pragma("unroll")                                                      \
        for (int s_ = 0; s_ < 2; ++s_) {                                       \
            const int off_ = s_ ? offA1 : offA0;                               \
            half8 a_[4];                                                       \
            _Pragma("unroll")                                                  \
            for (int i_ = 0; i_ < 4; ++i_)                                     \
                a_[i_] = *(const half8*)&zs[rA[i_] + off_];                    \
            _Pragma("unroll")                                                  \
            for (int j_ = 0; j_ < 4; ++j_) {                                   \
                const half8 bA_ = *(const half8*)&csA[rB[j_] + off_];          \
                _Pragma("unroll")                                              \
                for (int i_ = 0; i_ < 4; ++i_)                                 \
                    accA[i_][j_] = __builtin_amdgcn_mfma_f32_16x16x32_f16(     \
                        a_[i_], bA_, accA[i_][j_], 0, 0, 0);                   \
            }                                                                  \
            _Pragma("unroll")                                                  \
            for (int j_ = 0; j_ < 4; ++j_) {                                   \
                const half8 bB_ = *(const half8*)&csB[rB[j_] + off_];          \
                _Pragma("unroll")                                              \
                for (int i_ = 0; i_ < 4; ++i_)                                 \
                    accB[i_][j_] = __builtin_amdgcn_mfma_f32_16x16x32_f16(     \
                        a_[i_], bB_, accB[i_][j_], 0, 0, 0);                   \
            }                                                                  \
        }                                                                      \
        __syncthreads();                                                       \
    }

__global__ __launch_bounds__(256, 2)
void mfma_dist_kernel(const _Float16* __restrict__ zh, const _Float16* __restrict__ ch,
                      const float* __restrict__ esq,
                      float* __restrict__ pd1, float* __restrict__ pd2,
                      float* __restrict__ pd3,
                      int* __restrict__ pi1, int* __restrict__ pi2) {
    __shared__ _Float16 zs[BM * BK];    // 16 KB
    __shared__ _Float16 csA[BV * BK];   // 16 KB
    __shared__ _Float16 csB[BV * BK];   // 16 KB
    float* sc_d1 = (float*)zs;          // end-phase alias (5 KB, post-loop)
    float* sc_d2 = sc_d1 + BM * 2;
    float* sc_d3 = sc_d2 + BM * 2;
    int*   sc_i1 = (int*)(sc_d3 + BM * 2);
    int*   sc_i2 = sc_i1 + BM * 2;

    const int row0  = blockIdx.x * BM;
    const int vbase = blockIdx.y * VRANGE;

    const int tid  = threadIdx.x;
    const int w    = tid >> 6;
    const int lane = tid & 63;
    const int lr   = lane & 15;
    const int quad = lane >> 4;
    const int mh   = (w >> 1) * 64;
    const int vh   = (w & 1) * 64;

    const int q7   = quad ^ (lr & 7);
    const int offA0 = q7 * 8;
    const int offA1 = (4 ^ q7) * 8;
    int rA[4], rB[4];
    #pragma unroll
    for (int i = 0; i < 4; ++i) { rA[i] = (mh + i * 16 + lr) * BK; rB[i] = (vh + i * 16 + lr) * BK; }

    const int schunk = (lane & 7) ^ (lane >> 3);
    const _Float16* zsrc = zh + (size_t)(row0 + w * 32 + (lane >> 3)) * EMB + schunk * 8;

    float m1[16], m2[16], m3[16];
    #pragma unroll
    for (int t = 0; t < 16; ++t) { m1[t] = -INFINITY; m2[t] = -INFINITY; m3[t] = -INFINITY; }

    float evA[4], evB[4];
    #pragma unroll
    for (int j = 0; j < 4; ++j) {
        evA[j] = esq[vbase + vh + j * 16 + lr];
        evB[j] = esq[vbase + BV + vh + j * 16 + lr];
    }

    // prologue: stage (it=0, kt=0)
    {
        const _Float16* cA0 = ch + (size_t)(vbase + w * 32 + (lane >> 3)) * EMB + schunk * 8;
        const _Float16* cB0 = cA0 + (size_t)BV * EMB;
        #pragma unroll
        for (int q = 0; q < 4; ++q) {
            load_lds16(zsrc + (size_t)q * 8 * EMB, &zs [w * 2048 + q * 512]);
            load_lds16(cA0  + (size_t)q * 8 * EMB, &csA[w * 2048 + q * 512]);
            load_lds16(cB0  + (size_t)q * 8 * EMB, &csB[w * 2048 + q * 512]);
        }
    }

    for (int it = 0; it < NVT / 2; ++it) {
        const int vA = vbase + it * 2 * BV;
        const _Float16* csrcA = ch + (size_t)(vA + w * 32 + (lane >> 3)) * EMB + schunk * 8;
        const _Float16* csrcB = csrcA + (size_t)BV * EMB;

        floatx4 accA[4][4], accB[4][4];
        #pragma unroll
        for (int j = 0; j < 4; ++j) {
            const float eA = -0.5f * evA[j];
            const float eB = -0.5f * evB[j];
            #pragma unroll
            for (int i = 0; i < 4; ++i) { accA[i][j] = (floatx4)eA; accB[i][j] = (floatx4)eB; }
        }
        float evnA[4], evnB[4];
        {
            const int itn = (it + 1 < NVT / 2) ? it + 1 : it;
            #pragma unroll
            for (int j = 0; j < 4; ++j) {
                evnA[j] = esq[vbase + itn * 2 * BV + vh + j * 16 + lr];
                evnB[j] = esq[vbase + itn * 2 * BV + BV + vh + j * 16 + lr];
            }
        }

        // kt0 was staged earlier (prologue or previous it's boundary prefetch)
        KSTEP(0,      false)
        KSTEP(BK,     true)
        KSTEP(2 * BK, true)
        KSTEP(3 * BK, true)

        // boundary prefetch: stage (it+1, kt0) now; the tracking VALU below
        // (~224 wave-ops) covers the DMA latency before kt0's drain.
        if (it + 1 < NVT / 2) {
            const _Float16* nA = csrcA + (size_t)2 * BV * EMB;
            const _Float16* nB = nA + (size_t)BV * EMB;
            #pragma unroll
            for (int q = 0; q < 4; ++q) {
                load_lds16(zsrc + (size_t)q * 8 * EMB, &zs [w * 2048 + q * 512]);
                load_lds16(nA   + (size_t)q * 8 * EMB, &csA[w * 2048 + q * 512]);
                load_lds16(nB   + (size_t)q * 8 * EMB, &csB[w * 2048 + q * 512]);
            }
        }

        // top-3 insert, code = (it<<3)|(tileB<<2)|j in low 5 mantissa bits
        #pragma unroll
        for (int i = 0; i < 4; ++i) {
            #pragma unroll
            for (int reg = 0; reg < 4; ++reg) {
                const int t = i * 4 + reg;
                #pragma unroll
                for (int j = 0; j < 4; ++j) {
                    const unsigned code = ((unsigned)it << 3) | (unsigned)j;
                    const float a = __uint_as_float(
                        (__float_as_uint(accA[i][j][reg]) & ~31u) | code);
                    const float mid = fminf(m1[t], a);
                    m1[t] = fmaxf(m1[t], a);
                    const float lo  = fminf(m2[t], mid);
                    m2[t] = fmaxf(m2[t], mid);
                    m3[t] = fmaxf(m3[t], lo);
                }
                #pragma unroll
                for (int j = 0; j < 4; ++j) {
                    const unsigned code = ((unsigned)it << 3) | 4u | (unsigned)j;
                    const float a = __uint_as_float(
                        (__float_as_uint(accB[i][j][reg]) & ~31u) | code);
                    const float mid = fminf(m1[t], a);
                    m1[t] = fmaxf(m1[t], a);
                    const float lo  = fminf(m2[t], mid);
                    m2[t] = fmaxf(m2[t], mid);
                    m3[t] = fmaxf(m3[t], lo);
                }
            }
        }
        #pragma unroll
        for (int j = 0; j < 4; ++j) { evA[j] = evnA[j]; evB[j] = evnB[j]; }
    }

    // decode embedded codes -> indices (once, outside the hot loop)
    int i1[16], i2[16];
    #pragma unroll
    for (int t = 0; t < 16; ++t) {
        const unsigned c1 = __float_as_uint(m1[t]) & 31u;
        const unsigned c2 = __float_as_uint(m2[t]) & 31u;
        i1[t] = vbase + (int)(c1 >> 2) * BV + vh + (int)(c1 & 3u) * 16 + lr;
        i2[t] = vbase + (int)(c2 >> 2) * BV + vh + (int)(c2 & 3u) * 16 + lr;
    }

    // butterfly top-3 merge across the 16 lanes sharing a row
    #pragma unroll
    for (int t = 0; t < 16; ++t) {
        float a1 = m1[t], a2 = m2[t], a3 = m3[t]; int ii1 = i1[t], ii2 = i2[t];
        #pragma unroll
        for (int off = 1; off < 16; off <<= 1) {
            const float o1 = __shfl_xor(a1, off, 64);
            const float o2 = __shfl_xor(a2, off, 64);
            const float o3 = __shfl_xor(a3, off, 64);
            const int  oi1 = __shfl_xor(ii1, off, 64);
            const int  oi2 = __shfl_xor(ii2, off, 64);
            // insert o1
            const bool g1 = o1 > a1, g2 = o1 > a2, g3 = o1 > a3;
            a3  = g2 ? a2  : (g3 ? o1  : a3);
            a2  = g1 ? a1  : (g2 ? o1  : a2);
            ii2 = g1 ? ii1 : (g2 ? oi1 : ii2);
            a1  = g1 ? o1  : a1;
            ii1 = g1 ? oi1 : ii1;
            // insert o2 (o2 <= o1 <= a1 now)
            const bool h2 = o2 > a2, h3 = o2 > a3;
            a3  = h2 ? a2  : (h3 ? o2 : a3);
            a2  = h2 ? o2  : a2;
            ii2 = h2 ? oi2 : ii2;
            // insert o3 (o3 <= o2 <= a2 now: can only land in slot 3)
            a3 = fmaxf(a3, o3);
        }
        m1[t] = a1; m2[t] = a2; m3[t] = a3; i1[t] = ii1; i2[t] = ii2;
    }
    if (lr == 0) {
        #pragma unroll
        for (int t = 0; t < 16; ++t) {
            const int r = mh + (t >> 2) * 16 + quad * 4 + (t & 3);
            sc_d1[r * 2 + (w & 1)] = m1[t];
            sc_d2[r * 2 + (w & 1)] = m2[t];
            sc_d3[r * 2 + (w & 1)] = m3[t];
            sc_i1[r * 2 + (w & 1)] = i1[t];
            sc_i2[r * 2 + (w & 1)] = i2[t];
        }
    }
    __syncthreads();
    if (tid < BM) {
        float a1 = sc_d1[tid * 2], a2 = sc_d2[tid * 2], a3 = sc_d3[tid * 2];
        int  ii1 = sc_i1[tid * 2], ii2 = sc_i2[tid * 2];
        const float o1 = sc_d1[tid * 2 + 1], o2 = sc_d2[tid * 2 + 1], o3 = sc_d3[tid * 2 + 1];
        const int  oi1 = sc_i1[tid * 2 + 1], oi2 = sc_i2[tid * 2 + 1];
        {
            const bool g1 = o1 > a1, g2 = o1 > a2, g3 = o1 > a3;
            a3  = g2 ? a2  : (g3 ? o1  : a3);
            a2  = g1 ? a1  : (g2 ? o1  : a2);
            ii2 = g1 ? ii1 : (g2 ? oi1 : ii2);
            a1  = g1 ? o1  : a1;
            ii1 = g1 ? oi1 : ii1;
            const bool h2 = o2 > a2, h3 = o2 > a3;
            a3  = h2 ? a2  : (h3 ? o2 : a3);
            a2  = h2 ? o2  : a2;
            ii2 = h2 ? oi2 : ii2;
            a3 = fmaxf(a3, o3);
        }
        const size_t o = (size_t)blockIdx.y * N_ROWS + row0 + tid;
        pd1[o] = -2.0f * a1; pd2[o] = -2.0f * a2; pd3[o] = -2.0f * a3;
        pi1[o] = ii1; pi2[o] = ii2;
    }
}
#undef KSTEP

// ---------------------------------------------------------------------------
// Combine v2: merge VSPLIT top-3 partials.
//   margin >= TAU                      -> commit (fast path, ~98% of rows)
//   flagged & min_s d3_s >= g1 + TAU   -> clist (16-candidate fp32 rescore)
//   flagged & unsafe                   -> flist (full-vocab fallback, ~0 rows)
// ---------------------------------------------------------------------------
__global__ void combine_kernel(const float* __restrict__ pd1, const float* __restrict__ pd2,
                               const float* __restrict__ pd3, const int* __restrict__ pi1,
                               const float* __restrict__ cb,
                               float* __restrict__ tokens, float* __restrict__ zq,
                               float* __restrict__ cnt,
                               int* __restrict__ flagcnt,
                               int* __restrict__ clist, int* __restrict__ flist) {
    const int wave = threadIdx.x >> 6;
    const int lane = threadIdx.x & 63;
    const int row  = blockIdx.x * 4 + wave;

    float g1 = INFINITY, g2 = INFINITY, mind3 = INFINITY; int gi = 0;
    #pragma unroll
    for (int s = 0; s < VSPLIT; ++s) {
        const size_t o = (size_t)s * N_ROWS + row;
        const float od1 = pd1[o], od2 = pd2[o], od3 = pd3[o]; const int oi1 = pi1[o];
        if (od1 < g1) { g2 = fminf(g1, od2); g1 = od1; gi = oi1; }
        else          { g2 = fminf(g2, od1); }
        mind3 = fminf(mind3, od3);
    }
    if ((g2 - g1) < TAU) {
        if (lane == 0) {
            if (mind3 >= g1 + TAU) {        // candidates provably contain argmin
                const int pos = atomicAdd(&flagcnt[0], 1);
                clist[pos] = row;
            } else {                         // rare: needs full-vocab scan
                const int pos = atomicAdd(&flagcnt[1], 1);
                flist[pos] = row;
            }
        }
        return;   // rescue path writes this row
    }
    if (lane == 0) {
        tokens[row] = (float)gi;
        atomicAdd(&cnt[gi], 1.0f);
    }
    const float4 v = *(const float4*)(cb + (size_t)gi * EMB + lane * 4);
    *(float4*)(zq + (size_t)row * EMB + lane * 4) = v;
}

// ---------------------------------------------------------------------------
// Fused rescue: blocks [0, CAND_BLOCKS) run the 16-candidate fp32 rescore
// (clist rows, writes tokens/zq/cnt directly); blocks [CAND_BLOCKS, +512)
// run the full-vocab LDS-tiled fallback (flist rows, atomicMin into rkey).
// ---------------------------------------------------------------------------
#define RBV 64                       // codes per LDS tile
#define RSPLIT 4                     // row-split blocks per tile
#define NTILE (VOCAB / RBV)          // 128
#define CAND_BLOCKS 128
__global__ __launch_bounds__(256, 2)
void rescue_kernel(const int* __restrict__ flagcnt,
                   const int* __restrict__ clist, const int* __restrict__ flist,
                   const float* __restrict__ z, const float* __restrict__ cb,
                   const float* __restrict__ esq,
                   const int* __restrict__ pi1, const int* __restrict__ pi2,
                   float* __restrict__ tokens, float* __restrict__ zq,
                   float* __restrict__ cnt,
                   unsigned long long* __restrict__ rkey) {
    __shared__ float csf[RBV][EMB];   // 64 KB, full path only (swizzled chunks)

    const int tid  = threadIdx.x;
    const int w    = tid >> 6;
    const int lane = tid & 63;

    if (blockIdx.x < CAND_BLOCKS) {
        // ---- candidate rescore path ----
        const int n = flagcnt[0];
        const int c = lane >> 2;         // candidate slot 0..15
        const int s = lane & 3;          // dim quarter (64 dims each)

        for (int f = blockIdx.x * 4 + w; f < n; f += CAND_BLOCKS * 4) {
            const int row = clist[f];
            const size_t po = (size_t)(c & 7) * N_ROWS + row;
            const int cidx = (c < 8) ? pi1[po] : pi2[po];

            const float* zr = z  + (size_t)row  * EMB + s * 64;
            const float* cr = cb + (size_t)cidx * EMB + s * 64;
            float p0 = 0.0f, p1 = 0.0f, p2 = 0.0f, p3 = 0.0f;
            #pragma unroll
            for (int k = 0; k < 4; ++k) {
                const float4 z0 = *(const float4*)(zr + k * 16 + 0);
                const float4 c0 = *(const float4*)(cr + k * 16 + 0);
                const float4 z1 = *(const float4*)(zr + k * 16 + 4);
                const float4 c1 = *(const float4*)(cr + k * 16 + 4);
                const float4 z2 = *(const float4*)(zr + k * 16 + 8);
                const float4 c2 = *(const float4*)(cr + k * 16 + 8);
                const float4 z3 = *(const float4*)(zr + k * 16 + 12);
                const float4 c3 = *(const float4*)(cr + k * 16 + 12);
                p0 += z0.x * c0.x + z0.y * c0.y + z0.z * c0.z + z0.w * c0.w;
                p1 += z1.x * c1.x + z1.y * c1.y + z1.z * c1.z + z1.w * c1.w;
                p2 += z2.x * c2.x + z2.y * c2.y + z2.z * c2.z + z2.w * c2.w;
                p3 += z3.x * c3.x + z3.y * c3.y + z3.z * c3.z + z3.w * c3.w;
            }
            float p = (p0 + p1) + (p2 + p3);
            p += __shfl_xor(p, 1, 64);
            p += __shfl_xor(p, 2, 64);   // full dot in all 4 quad lanes

            float bd = esq[cidx] - 2.0f * p;
            int   bv = cidx;
            #pragma unroll
            for (int off = 4; off < 64; off <<= 1) {
                const float od = __shfl_xor(bd, off, 64);
                const int   ov = __shfl_xor(bv, off, 64);
                if (od < bd || (od == bd && ov < bv)) { bd = od; bv = ov; }
            }
            if (lane == 0) {
                tokens[row] = (float)bv;
                atomicAdd(&cnt[bv], 1.0f);
            }
            const float4 c4 = *(const float4*)(cb + (size_t)bv * EMB + lane * 4);
            *(float4*)(zq + (size_t)row * EMB + lane * 4) = c4;
        }
        return;
    }

    // ---- full-vocab fallback path (expected n ~ 0) ----
    const int n = __builtin_amdgcn_readfirstlane(flagcnt[1]);
    if (n == 0) return;

    const int bid  = blockIdx.x - CAND_BLOCKS;
    const int tile = bid >> 2;               // 0..127
    const int rs   = bid & 3;                // 0..3
    const int c0   = tile * RBV;
    const int g    = lane >> 2;              // code group 0..15
    const int s    = lane & 3;               // dim quarter within 16-chunk

    #pragma unroll
    for (int i = 0; i < 16; ++i) {
        const int code = i * 4 + w;
        const float4 v = *(const float4*)(cb + (size_t)(c0 + code) * EMB + lane * 4);
        *(float4*)&csf[code][(lane ^ (code & 7)) * 4] = v;
    }
    __syncthreads();

    const int nq = (n + 3) >> 2;
    const int q0 = (rs << 2) | w;
    if (q0 >= nq) return;                    // after barrier; wave-uniform

    float ev[4];
    #pragma unroll
    for (int gs = 0; gs < 4; ++gs) ev[gs] = esq[c0 + gs * 16 + g];

    for (int q = q0; q < nq; q += 16) {
        int rows[4];
        #pragma unroll
        for (int r = 0; r < 4; ++r) {
            const int fi = q * 4 + r;
            rows[r] = __builtin_amdgcn_readfirstlane(flist[fi < n ? fi : 0]);
        }

        float p[4][4];                        // [gs][row]
        #pragma unroll
        for (int gs = 0; gs < 4; ++gs)
            #pragma unroll
            for (int r = 0; r < 4; ++r) p[gs][r] = 0.0f;

        #pragma unroll
        for (int kb = 0; kb < 4; ++kb) {
            #pragma unroll
            for (int kk = 0; kk < 4; ++kk) {
                const int dbase = (kb * 4 + kk) * 16 + s * 4;
                float4 zv[4];
                #pragma unroll
                for (int r = 0; r < 4; ++r)
                    zv[r] = *(const float4*)(z + (size_t)rows[r] * EMB + dbase);
                const int dq = (kb * 4 + kk) * 4 + s;
                #pragma unroll
                for (int gs = 0; gs < 4; ++gs) {
                    const int code = gs * 16 + g;
                    const float4 c4 = *(const float4*)&csf[code][(dq ^ (code & 7)) * 4];
                    #pragma unroll
                    for (int r = 0; r < 4; ++r)
                        p[gs][r] += zv[r].x * c4.x + zv[r].y * c4.y
                                  + zv[r].z * c4.z + zv[r].w * c4.w;
                }
            }
        }

        #pragma unroll
        for (int gs = 0; gs < 4; ++gs)
            #pragma unroll
            for (int r = 0; r < 4; ++r) {
                float t = p[gs][r];
                t += __shfl_xor(t, 1, 64);
                t += __shfl_xor(t, 2, 64);
                p[gs][r] = t;
            }

        #pragma unroll
        for (int r = 0; r < 4; ++r) {
            float bd = INFINITY; int bv = 0;
            #pragma unroll
            for (int gs = 0; gs < 4; ++gs) {
                const float d = ev[gs] - 2.0f * p[gs][r];
                const int v = c0 + gs * 16 + g;
                if (d < bd) { bd = d; bv = v; }
            }
            #pragma unroll
            for (int off = 4; off < 64; off <<= 1) {
                const float od = __shfl_xor(bd, off, 64);
                const int   ov = __shfl_xor(bv, off, 64);
                if (od < bd || (od == bd && ov < bv)) { bd = od; bv = ov; }
            }
            if (lane == 0 && q * 4 + r < n) {
                unsigned int u = __float_as_uint(bd);
                u = (u & 0x80000000u) ? ~u : (u | 0x80000000u);
                atomicMin(rkey + rows[r], ((unsigned long long)u << 32) | (unsigned int)bv);
            }
        }
    }
}

// ---------------------------------------------------------------------------
// Full-scan writer: separate dispatch (kernel boundary = visibility ordering).
// ---------------------------------------------------------------------------
__global__ void rescue_write_kernel(const int* __restrict__ flagcnt,
                                    const int* __restrict__ flist,
                                    const unsigned long long* __restrict__ rkey,
                                    const float* __restrict__ cb,
                                    float* __restrict__ tokens, float* __restrict__ zq,
                                    float* __restrict__ cnt) {
    const int w    = threadIdx.x >> 6;
    const int lane = threadIdx.x & 63;
    const int n = flagcnt[1];
    for (int f = blockIdx.x * 4 + w; f < n; f += gridDim.x * 4) {
        const int row = flist[f];
        const int v = (int)(unsigned int)(rkey[row] & 0xFFFFFFFFull);
        if (lane == 0) {
            tokens[row] = (float)v;
            atomicAdd(&cnt[v], 1.0f);
        }
        const float4 c4 = *(const float4*)(cb + (size_t)v * EMB + lane * 4);
        *(float4*)(zq + (size_t)row * EMB + lane * 4) = c4;
    }
}

// ===========================================================================
// Fallback (round-3 fp32 path) if ws is too small.
// ===========================================================================
__global__ void esq_kernel(const float* __restrict__ cb, float* __restrict__ esq) {
    const int wave = threadIdx.x >> 6;
    const int lane = threadIdx.x & 63;
    const int row  = blockIdx.x * 4 + wave;
    const float4 v = *(const float4*)(cb + (size_t)row * EMB + lane * 4);
    float s = v.x * v.x + v.y * v.y + v.z * v.z + v.w * v.w;
    #pragma unroll
    for (int off = 32; off > 0; off >>= 1) s += __shfl_down(s, off, 64);
    if (lane == 0) esq[row] = s;
}

#define FLSTR 36
__global__ __launch_bounds__(256, 2)
void fb_dist_kernel(const float* __restrict__ z, const float* __restrict__ cb,
                    const float* __restrict__ esq,
                    float* __restrict__ pdist, int* __restrict__ pidx) {
    __shared__ float zs[BM][FLSTR];
    __shared__ float es[BV][FLSTR];
    __shared__ float rdist[16][16];
    __shared__ int   ridx [16][16];
    const int row0 = blockIdx.x * BM, vbase = blockIdx.y * VRANGE;
    const int tid = threadIdx.x, wave = tid >> 6, lane = tid & 63;
    const int wly = (lane >> 3) & 7, wlx = lane & 7;
    const int wbase = (wave >> 1) * 64, cbase = (wave & 1) * 64;
    const int arow = wbase + wly, bcol = cbase + wlx;
    const int rowSlot = (wave >> 1) * 8 + wly, colSlot = (wave & 1) * 8 + wlx;
    const int sc4 = tid & 7, sr0 = tid >> 3;
    float best[8]; int bidx[8];
    #pragma unroll
    for (int i = 0; i < 8; ++i) { best[i] = INFINITY; bidx[i] = 0; }
    for (int vt = 0; vt < NVT; ++vt) {
        const int v0 = vbase + vt * BV;
        float acc[8][8];
        #pragma unroll
        for (int i = 0; i < 8; ++i)
            #pragma unroll
            for (int j = 0; j < 8; ++j) acc[i][j] = 0.0f;
        #pragma unroll 1
        for (int kt = 0; kt < EMB / 32; ++kt) {
            #pragma unroll
            for (int t = 0; t < 4; ++t) {
                const int r = sr0 + 32 * t;
                *(float4*)&zs[r][sc4 * 4] = *(const float4*)(z  + (size_t)(row0 + r) * EMB + kt * 32 + sc4 * 4);
                *(float4*)&es[r][sc4 * 4] = *(const float4*)(cb + (size_t)(v0 + r) * EMB + kt * 32 + sc4 * 4);
            }
            __syncthreads();
            #pragma unroll 1
            for (int k0 = 0; k0 < 8; ++k0) {
                const int kk = k0 * 4;
                float a[8][4];
                #pragma unroll
                for (int i = 0; i < 8; ++i) {
                    const float4 a4 = *(const float4*)&zs[arow + 8 * i][kk];
                    a[i][0] = a4.x; a[i][1] = a4.y; a[i][2] = a4.z; a[i][3] = a4.w;
                }
                #pragma unroll
                for (int j = 0; j < 8; ++j) {
                    const float4 b4 = *(const float4*)&es[bcol + 8 * j][kk];
                    #pragma unroll
                    for (int i = 0; i < 8; ++i) {
                        acc[i][j] += a[i][0] * b4.x; acc[i][j] += a[i][1] * b4.y;
                        acc[i][j] += a[i][2] * b4.z; acc[i][j] += a[i][3] * b4.w;
                    }
                }
            }
            __syncthreads();
        }
        #pragma unroll
        for (int j = 0; j < 8; ++j) {
            const int v = v0 + bcol + 8 * j;
            const float evv = esq[v];
            #pragma unroll
            for (int i = 0; i < 8; ++i) {
                const float d = evv - 2.0f * acc[i][j];
                if (d < best[i]) { best[i] = d; bidx[i] = v; }
            }
        }
    }
    for (int i = 0; i < 8; ++i) {
        rdist[rowSlot][colSlot] = best[i];
        ridx [rowSlot][colSlot] = bidx[i];
        __syncthreads();
        if (colSlot == 0) {
            float bd = rdist[rowSlot][0]; int bi = ridx[rowSlot][0];
            #pragma unroll
            for (int t = 1; t < 16; ++t) {
                const float d = rdist[rowSlot][t]; const int ii = ridx[rowSlot][t];
                if (d < bd || (d == bd && ii < bi)) { bd = d; bi = ii; }
            }
            const int row = row0 + wbase + 8 * i + wly;
            pdist[(size_t)blockIdx.y * N_ROWS + row] = bd;
            pidx [(size_t)blockIdx.y * N_ROWS + row] = bi;
        }
        __syncthreads();
    }
}

__global__ void fb_combine_kernel(const float* __restrict__ pdist, const int* __restrict__ pidx,
                                  const float* __restrict__ cb,
                                  float* __restrict__ tokens, float* __restrict__ zq,
                                  float* __restrict__ cnt) {
    const int wave = threadIdx.x >> 6, lane = threadIdx.x & 63;
    const int row = blockIdx.x * 4 + wave;
    float bd = INFINITY; int bi = 0;
    #pragma unroll
    for (int s = 0; s < VSPLIT; ++s) {
        const float d = pdist[(size_t)s * N_ROWS + row];
        const int ii  = pidx [(size_t)s * N_ROWS + row];
        if (d < bd || (d == bd && ii < bi)) { bd = d; bi = ii; }
    }
    if (lane == 0) { tokens[row] = (float)bi; atomicAdd(&cnt[bi], 1.0f); }
    const float4 v = *(const float4*)(cb + (size_t)bi * EMB + lane * 4);
    *(float4*)(zq + (size_t)row * EMB + lane * 4) = v;
}

// ---------------------------------------------------------------------------
// d_out: [0,N) tokens | [N, N+N*EMB) zq | +VOCAB ref_count
// ws: zh | ch | esq | pd1|pd2|pd3|pi1|pi2 | rkey | counters | clist | flist
// 5 dispatches: prep -> mfma_dist -> combine -> rescue(fused) -> rescue_write
// ---------------------------------------------------------------------------
extern "C" void kernel_launch(void* const* d_in, const int* in_sizes, int n_in,
                              void* d_out, int out_size, void* d_ws, size_t ws_size,
                              hipStream_t stream) {
    const float* z  = (const float*)d_in[0];
    const float* cb = (const float*)d_in[1];

    float* out    = (float*)d_out;
    float* tokens = out;
    float* zq     = out + N_ROWS;
    float* cnt    = out + N_ROWS + (size_t)N_ROWS * EMB;

    const size_t ZE = (size_t)N_ROWS * EMB, CE = (size_t)VOCAB * EMB, P = (size_t)VSPLIT * N_ROWS;
    const size_t NEED = (ZE + CE) * sizeof(_Float16) + VOCAB * 4
                      + 5 * P * 4 + (size_t)N_ROWS * 8 + 256 + 2 * (size_t)N_ROWS * 4;

    if (ws_size >= NEED) {
        char* p = (char*)d_ws;
        _Float16* zh = (_Float16*)p;            p += ZE * 2;
        _Float16* ch = (_Float16*)p;            p += CE * 2;
        float* esq   = (float*)p;               p += VOCAB * 4;
        float* pd1   = (float*)p;               p += P * 4;
        float* pd2   = (float*)p;               p += P * 4;
        float* pd3   = (float*)p;               p += P * 4;
        int*   pi1   = (int*)p;                 p += P * 4;
        int*   pi2   = (int*)p;                 p += P * 4;
        unsigned long long* rkey = (unsigned long long*)p;  p += (size_t)N_ROWS * 8;
        int*   flagcnt = (int*)p;               p += 256;
        int*   clist = (int*)p;                 p += (size_t)N_ROWS * 4;
        int*   flist = (int*)p;

        prep_kernel<<<VOCAB / 4 + (int)(ZE / 4 / 256), 256, 0, stream>>>(
            z, cb, zh, ch, esq, cnt, rkey, flagcnt);
        mfma_dist_kernel<<<dim3(N_ROWS / BM, VSPLIT), 256, 0, stream>>>(
            zh, ch, esq, pd1, pd2, pd3, pi1, pi2);
        combine_kernel<<<N_ROWS / 4, 256, 0, stream>>>(
            pd1, pd2, pd3, pi1, cb, tokens, zq, cnt, flagcnt, clist, flist);
        rescue_kernel<<<CAND_BLOCKS + NTILE * RSPLIT, 256, 0, stream>>>(
            flagcnt, clist, flist, z, cb, esq, pi1, pi2, tokens, zq, cnt, rkey);
        rescue_write_kernel<<<32, 256, 0, stream>>>(
            flagcnt, flist, rkey, cb, tokens, zq, cnt);
    } else {
        float* esq   = (float*)d_ws;
        float* pdist = esq + VOCAB;
        int*   pidx  = (int*)(pdist + P);
        hipMemsetAsync(cnt, 0, VOCAB * sizeof(float), stream);
        esq_kernel<<<VOCAB / 4, 256, 0, stream>>>(cb, esq);
        fb_dist_kernel<<<dim3(N_ROWS / BM, VSPLIT), 256, 0, stream>>>(z, cb, esq, pdist, pidx);
        fb_combine_kernel<<<N_ROWS / 4, 256, 0, stream>>>(pdist, pidx, cb, tokens, zq, cnt);
    }
}

// Round 11
// 192.182 us; speedup vs baseline: 1.5331x; 1.5331x over previous
//
#include <hip/hip_runtime.h>
#include <math.h>

#define N_ROWS 16384
#define VOCAB  8192
#define EMB    256

// ---- MFMA path tiling ----
#define BM 128
#define BV 128
#define BK 64                      // halfs per staged K-chunk (2 MFMA k-steps)
#define VSPLIT 8                   // grid (128, 8)
#define VRANGE (VOCAB / VSPLIT)    // 1024
#define NVT    (VRANGE / BV)       // 8
#define TAU 0.15f                  // rescue margin: >= 2*max|dist err| (fp16 inputs)

typedef _Float16 half8 __attribute__((ext_vector_type(8)));
typedef _Float16 half4 __attribute__((ext_vector_type(4)));
typedef float floatx4 __attribute__((ext_vector_type(4)));

// async global->LDS DMA, 16 B/lane; LDS dest = wave-uniform base + lane*16
__device__ __forceinline__ void load_lds16(const _Float16* g, _Float16* l) {
    __builtin_amdgcn_global_load_lds(
        (const __attribute__((address_space(1))) void*)g,
        (__attribute__((address_space(3))) void*)l, 16, 0, 0);
}

// ---------------------------------------------------------------------------
// PREP (1 dispatch replaces esq + split + memsets).
// counters: flagcnt[0] = candidate-rescore count, flagcnt[1] = full-scan count
// ---------------------------------------------------------------------------
__global__ void prep_kernel(const float* __restrict__ z, const float* __restrict__ cb,
                            _Float16* __restrict__ zh, _Float16* __restrict__ ch,
                            float* __restrict__ esq, float* __restrict__ cnt,
                            unsigned long long* __restrict__ rkey,
                            int* __restrict__ flagcnt) {
    const int b = blockIdx.x, t = threadIdx.x;
    if (b < VOCAB / 4) {
        const int row  = b * 4 + (t >> 6);
        const int lane = t & 63;
        const float4 f = *(const float4*)(cb + (size_t)row * EMB + lane * 4);
        half4 h;
        h.x = (_Float16)f.x; h.y = (_Float16)f.y; h.z = (_Float16)f.z; h.w = (_Float16)f.w;
        *(half4*)(ch + (size_t)row * EMB + lane * 4) = h;
        float s = f.x * f.x + f.y * f.y + f.z * f.z + f.w * f.w;
        #pragma unroll
        for (int off = 32; off > 0; off >>= 1) s += __shfl_down(s, off, 64);
        if (lane == 0) esq[row] = s;
        if (t < 4) cnt[b * 4 + t] = 0.0f;
        if (t >= 8 && t < 16) rkey[b * 8 + (t - 8)] = ~0ull;
        if (b == 0 && t == 4) flagcnt[0] = 0;
        if (b == 0 && t == 5) flagcnt[1] = 0;
    } else {
        const size_t idx4 = (size_t)(b - VOCAB / 4) * 256 + t;
        const float4 f = *(const float4*)(z + idx4 * 4);
        half4 h;
        h.x = (_Float16)f.x; h.y = (_Float16)f.y; h.z = (_Float16)f.z; h.w = (_Float16)f.w;
        *(half4*)(zh + idx4 * 4) = h;
    }
}

// ---------------------------------------------------------------------------
// MFMA dist kernel v14 (PROVEN 114.6us, locked): DUAL V-TILE per staging
// round. Per iteration stage {z, cA, cB} slices (12 loads), ONE barrier
// pair, 32 MFMA (2 tiles sharing the A fragments) — halves drain events
// (32->16) vs v13 and halves z re-staging. Register budget 124 VGPR +
// 128 AGPR = 252/256 @ (256,2): ZERO headroom — r10's boundary prefetch
// (+4 regs) spilled (WRITE 2.56->140 MB, 207us). DO NOT insert anything
// into the accA/accB live range. r9's single-sync dbuf also regressed
// (one step's MFMA can't cover ~500cy DMA latency). This is the measured
// local optimum of the 2-barrier structure.
// Tracking: mantissa-embedded codes (it<<3)|(tb<<2)|j in low 5 bits; pure
// min/max network (7 VALU/val); decode once after the loop. Perturbation
// <=32 ulp << TAU; ties resolved by exact fp32 candidate rescore.
// ---------------------------------------------------------------------------
__global__ __launch_bounds__(256, 2)
void mfma_dist_kernel(const _Float16* __restrict__ zh, const _Float16* __restrict__ ch,
                      const float* __restrict__ esq,
                      float* __restrict__ pd1, float* __restrict__ pd2,
                      float* __restrict__ pd3,
                      int* __restrict__ pi1, int* __restrict__ pi2) {
    __shared__ _Float16 zs[BM * BK];    // 16 KB
    __shared__ _Float16 csA[BV * BK];   // 16 KB
    __shared__ _Float16 csB[BV * BK];   // 16 KB
    float* sc_d1 = (float*)zs;          // end-phase alias (5 KB, post-loop)
    float* sc_d2 = sc_d1 + BM * 2;
    float* sc_d3 = sc_d2 + BM * 2;
    int*   sc_i1 = (int*)(sc_d3 + BM * 2);
    int*   sc_i2 = sc_i1 + BM * 2;

    const int row0  = blockIdx.x * BM;
    const int vbase = blockIdx.y * VRANGE;

    const int tid  = threadIdx.x;
    const int w    = tid >> 6;
    const int lane = tid & 63;
    const int lr   = lane & 15;
    const int quad = lane >> 4;
    const int mh   = (w >> 1) * 64;
    const int vh   = (w & 1) * 64;

    const int q7   = quad ^ (lr & 7);
    const int offA0 = q7 * 8;
    const int offA1 = (4 ^ q7) * 8;
    int rA[4], rB[4];
    #pragma unroll
    for (int i = 0; i < 4; ++i) { rA[i] = (mh + i * 16 + lr) * BK; rB[i] = (vh + i * 16 + lr) * BK; }

    const int schunk = (lane & 7) ^ (lane >> 3);
    const _Float16* zsrc = zh + (size_t)(row0 + w * 32 + (lane >> 3)) * EMB + schunk * 8;

    float m1[16], m2[16], m3[16];
    #pragma unroll
    for (int t = 0; t < 16; ++t) { m1[t] = -INFINITY; m2[t] = -INFINITY; m3[t] = -INFINITY; }

    float evA[4], evB[4];
    #pragma unroll
    for (int j = 0; j < 4; ++j) {
        evA[j] = esq[vbase + vh + j * 16 + lr];
        evB[j] = esq[vbase + BV + vh + j * 16 + lr];
    }

    for (int it = 0; it < NVT / 2; ++it) {
        const int vA = vbase + it * 2 * BV;
        const _Float16* csrcA = ch + (size_t)(vA + w * 32 + (lane >> 3)) * EMB + schunk * 8;
        const _Float16* csrcB = csrcA + (size_t)BV * EMB;

        floatx4 accA[4][4], accB[4][4];
        #pragma unroll
        for (int j = 0; j < 4; ++j) {
            const float eA = -0.5f * evA[j];
            const float eB = -0.5f * evB[j];
            #pragma unroll
            for (int i = 0; i < 4; ++i) { accA[i][j] = (floatx4)eA; accB[i][j] = (floatx4)eB; }
        }
        float evnA[4], evnB[4];
        {
            const int itn = (it + 1 < NVT / 2) ? it + 1 : it;
            #pragma unroll
            for (int j = 0; j < 4; ++j) {
                evnA[j] = esq[vbase + itn * 2 * BV + vh + j * 16 + lr];
                evnB[j] = esq[vbase + itn * 2 * BV + BV + vh + j * 16 + lr];
            }
        }

        #pragma unroll 1
        for (int kt = 0; kt < EMB / BK; ++kt) {
            const int ko = kt * BK;
            #pragma unroll
            for (int q = 0; q < 4; ++q) {
                load_lds16(zsrc  + (size_t)q * 8 * EMB + ko, &zs [w * 2048 + q * 512]);
                load_lds16(csrcA + (size_t)q * 8 * EMB + ko, &csA[w * 2048 + q * 512]);
                load_lds16(csrcB + (size_t)q * 8 * EMB + ko, &csB[w * 2048 + q * 512]);
            }
            __syncthreads();

            #pragma unroll
            for (int s = 0; s < 2; ++s) {
                const int off = s ? offA1 : offA0;
                half8 a[4];
                #pragma unroll
                for (int i = 0; i < 4; ++i) a[i] = *(const half8*)&zs[rA[i] + off];
                #pragma unroll
                for (int j = 0; j < 4; ++j) {
                    const half8 bA = *(const half8*)&csA[rB[j] + off];
                    #pragma unroll
                    for (int i = 0; i < 4; ++i)
                        accA[i][j] = __builtin_amdgcn_mfma_f32_16x16x32_f16(a[i], bA, accA[i][j], 0, 0, 0);
                }
                #pragma unroll
                for (int j = 0; j < 4; ++j) {
                    const half8 bB = *(const half8*)&csB[rB[j] + off];
                    #pragma unroll
                    for (int i = 0; i < 4; ++i)
                        accB[i][j] = __builtin_amdgcn_mfma_f32_16x16x32_f16(a[i], bB, accB[i][j], 0, 0, 0);
                }
            }
            __syncthreads();
        }

        // top-3 insert, code = (it<<3)|(tileB<<2)|j in low 5 mantissa bits
        #pragma unroll
        for (int i = 0; i < 4; ++i) {
            #pragma unroll
            for (int reg = 0; reg < 4; ++reg) {
                const int t = i * 4 + reg;
                #pragma unroll
                for (int j = 0; j < 4; ++j) {
                    const unsigned code = ((unsigned)it << 3) | (unsigned)j;
                    const float a = __uint_as_float(
                        (__float_as_uint(accA[i][j][reg]) & ~31u) | code);
                    const float mid = fminf(m1[t], a);
                    m1[t] = fmaxf(m1[t], a);
                    const float lo  = fminf(m2[t], mid);
                    m2[t] = fmaxf(m2[t], mid);
                    m3[t] = fmaxf(m3[t], lo);
                }
                #pragma unroll
                for (int j = 0; j < 4; ++j) {
                    const unsigned code = ((unsigned)it << 3) | 4u | (unsigned)j;
                    const float a = __uint_as_float(
                        (__float_as_uint(accB[i][j][reg]) & ~31u) | code);
                    const float mid = fminf(m1[t], a);
                    m1[t] = fmaxf(m1[t], a);
                    const float lo  = fminf(m2[t], mid);
                    m2[t] = fmaxf(m2[t], mid);
                    m3[t] = fmaxf(m3[t], lo);
                }
            }
        }
        #pragma unroll
        for (int j = 0; j < 4; ++j) { evA[j] = evnA[j]; evB[j] = evnB[j]; }
    }

    // decode embedded codes -> indices (once, outside the hot loop)
    int i1[16], i2[16];
    #pragma unroll
    for (int t = 0; t < 16; ++t) {
        const unsigned c1 = __float_as_uint(m1[t]) & 31u;
        const unsigned c2 = __float_as_uint(m2[t]) & 31u;
        i1[t] = vbase + (int)(c1 >> 2) * BV + vh + (int)(c1 & 3u) * 16 + lr;
        i2[t] = vbase + (int)(c2 >> 2) * BV + vh + (int)(c2 & 3u) * 16 + lr;
    }

    // butterfly top-3 merge across the 16 lanes sharing a row
    #pragma unroll
    for (int t = 0; t < 16; ++t) {
        float a1 = m1[t], a2 = m2[t], a3 = m3[t]; int ii1 = i1[t], ii2 = i2[t];
        #pragma unroll
        for (int off = 1; off < 16; off <<= 1) {
            const float o1 = __shfl_xor(a1, off, 64);
            const float o2 = __shfl_xor(a2, off, 64);
            const float o3 = __shfl_xor(a3, off, 64);
            const int  oi1 = __shfl_xor(ii1, off, 64);
            const int  oi2 = __shfl_xor(ii2, off, 64);
            // insert o1
            const bool g1 = o1 > a1, g2 = o1 > a2, g3 = o1 > a3;
            a3  = g2 ? a2  : (g3 ? o1  : a3);
            a2  = g1 ? a1  : (g2 ? o1  : a2);
            ii2 = g1 ? ii1 : (g2 ? oi1 : ii2);
            a1  = g1 ? o1  : a1;
            ii1 = g1 ? oi1 : ii1;
            // insert o2 (o2 <= o1 <= a1 now)
            const bool h2 = o2 > a2, h3 = o2 > a3;
            a3  = h2 ? a2  : (h3 ? o2 : a3);
            a2  = h2 ? o2  : a2;
            ii2 = h2 ? oi2 : ii2;
            // insert o3 (o3 <= o2 <= a2 now: can only land in slot 3)
            a3 = fmaxf(a3, o3);
        }
        m1[t] = a1; m2[t] = a2; m3[t] = a3; i1[t] = ii1; i2[t] = ii2;
    }
    if (lr == 0) {
        #pragma unroll
        for (int t = 0; t < 16; ++t) {
            const int r = mh + (t >> 2) * 16 + quad * 4 + (t & 3);
            sc_d1[r * 2 + (w & 1)] = m1[t];
            sc_d2[r * 2 + (w & 1)] = m2[t];
            sc_d3[r * 2 + (w & 1)] = m3[t];
            sc_i1[r * 2 + (w & 1)] = i1[t];
            sc_i2[r * 2 + (w & 1)] = i2[t];
        }
    }
    __syncthreads();
    if (tid < BM) {
        float a1 = sc_d1[tid * 2], a2 = sc_d2[tid * 2], a3 = sc_d3[tid * 2];
        int  ii1 = sc_i1[tid * 2], ii2 = sc_i2[tid * 2];
        const float o1 = sc_d1[tid * 2 + 1], o2 = sc_d2[tid * 2 + 1], o3 = sc_d3[tid * 2 + 1];
        const int  oi1 = sc_i1[tid * 2 + 1], oi2 = sc_i2[tid * 2 + 1];
        {
            const bool g1 = o1 > a1, g2 = o1 > a2, g3 = o1 > a3;
            a3  = g2 ? a2  : (g3 ? o1  : a3);
            a2  = g1 ? a1  : (g2 ? o1  : a2);
            ii2 = g1 ? ii1 : (g2 ? oi1 : ii2);
            a1  = g1 ? o1  : a1;
            ii1 = g1 ? oi1 : ii1;
            const bool h2 = o2 > a2, h3 = o2 > a3;
            a3  = h2 ? a2  : (h3 ? o2 : a3);
            a2  = h2 ? o2  : a2;
            ii2 = h2 ? oi2 : ii2;
            a3 = fmaxf(a3, o3);
        }
        const size_t o = (size_t)blockIdx.y * N_ROWS + row0 + tid;
        pd1[o] = -2.0f * a1; pd2[o] = -2.0f * a2; pd3[o] = -2.0f * a3;
        pi1[o] = ii1; pi2[o] = ii2;
    }
}

// ---------------------------------------------------------------------------
// Combine v2: merge VSPLIT top-3 partials.
//   margin >= TAU                      -> commit (fast path, ~98% of rows)
//   flagged & min_s d3_s >= g1 + TAU   -> clist (16-candidate fp32 rescore)
//   flagged & unsafe                   -> flist (full-vocab fallback, ~0 rows)
// ---------------------------------------------------------------------------
__global__ void combine_kernel(const float* __restrict__ pd1, const float* __restrict__ pd2,
                               const float* __restrict__ pd3, const int* __restrict__ pi1,
                               const float* __restrict__ cb,
                               float* __restrict__ tokens, float* __restrict__ zq,
                               float* __restrict__ cnt,
                               int* __restrict__ flagcnt,
                               int* __restrict__ clist, int* __restrict__ flist) {
    const int wave = threadIdx.x >> 6;
    const int lane = threadIdx.x & 63;
    const int row  = blockIdx.x * 4 + wave;

    float g1 = INFINITY, g2 = INFINITY, mind3 = INFINITY; int gi = 0;
    #pragma unroll
    for (int s = 0; s < VSPLIT; ++s) {
        const size_t o = (size_t)s * N_ROWS + row;
        const float od1 = pd1[o], od2 = pd2[o], od3 = pd3[o]; const int oi1 = pi1[o];
        if (od1 < g1) { g2 = fminf(g1, od2); g1 = od1; gi = oi1; }
        else          { g2 = fminf(g2, od1); }
        mind3 = fminf(mind3, od3);
    }
    if ((g2 - g1) < TAU) {
        if (lane == 0) {
            if (mind3 >= g1 + TAU) {        // candidates provably contain argmin
                const int pos = atomicAdd(&flagcnt[0], 1);
                clist[pos] = row;
            } else {                         // rare: needs full-vocab scan
                const int pos = atomicAdd(&flagcnt[1], 1);
                flist[pos] = row;
            }
        }
        return;   // rescue path writes this row
    }
    if (lane == 0) {
        tokens[row] = (float)gi;
        atomicAdd(&cnt[gi], 1.0f);
    }
    const float4 v = *(const float4*)(cb + (size_t)gi * EMB + lane * 4);
    *(float4*)(zq + (size_t)row * EMB + lane * 4) = v;
}

// ---------------------------------------------------------------------------
// Candidate rescore: one wave per flagged row; exact fp32 dist for the 16
// tracked candidates (pi1/pi2 x 8 splits); argmin with lowest-index ties.
// Work/row: 16 codes x 256 dims = 4096 FMA + 17 KB reads (vs 8 MB full scan).
// ---------------------------------------------------------------------------
__global__ void rescue_cand_kernel(const int* __restrict__ flagcnt,
                                   const int* __restrict__ clist,
                                   const float* __restrict__ z, const float* __restrict__ cb,
                                   const float* __restrict__ esq,
                                   const int* __restrict__ pi1, const int* __restrict__ pi2,
                                   float* __restrict__ tokens, float* __restrict__ zq,
                                   float* __restrict__ cnt) {
    const int n    = flagcnt[0];
    const int w    = threadIdx.x >> 6;
    const int lane = threadIdx.x & 63;
    const int c    = lane >> 2;          // candidate slot 0..15
    const int s    = lane & 3;           // dim quarter (64 dims each)

    for (int f = blockIdx.x * 4 + w; f < n; f += gridDim.x * 4) {
        const int row = clist[f];
        const size_t po = (size_t)(c & 7) * N_ROWS + row;
        const int cidx = (c < 8) ? pi1[po] : pi2[po];

        const float* zr = z  + (size_t)row  * EMB + s * 64;
        const float* cr = cb + (size_t)cidx * EMB + s * 64;
        float p0 = 0.0f, p1 = 0.0f, p2 = 0.0f, p3 = 0.0f;
        #pragma unroll
        for (int k = 0; k < 4; ++k) {
            const float4 z0 = *(const float4*)(zr + k * 16 + 0);
            const float4 c0 = *(const float4*)(cr + k * 16 + 0);
            const float4 z1 = *(const float4*)(zr + k * 16 + 4);
            const float4 c1 = *(const float4*)(cr + k * 16 + 4);
            const float4 z2 = *(const float4*)(zr + k * 16 + 8);
            const float4 c2 = *(const float4*)(cr + k * 16 + 8);
            const float4 z3 = *(const float4*)(zr + k * 16 + 12);
            const float4 c3 = *(const float4*)(cr + k * 16 + 12);
            p0 += z0.x * c0.x + z0.y * c0.y + z0.z * c0.z + z0.w * c0.w;
            p1 += z1.x * c1.x + z1.y * c1.y + z1.z * c1.z + z1.w * c1.w;
            p2 += z2.x * c2.x + z2.y * c2.y + z2.z * c2.z + z2.w * c2.w;
            p3 += z3.x * c3.x + z3.y * c3.y + z3.z * c3.z + z3.w * c3.w;
        }
        float p = (p0 + p1) + (p2 + p3);
        p += __shfl_xor(p, 1, 64);
        p += __shfl_xor(p, 2, 64);       // full dot in all 4 quad lanes

        float bd = esq[cidx] - 2.0f * p;
        int   bv = cidx;
        #pragma unroll
        for (int off = 4; off < 64; off <<= 1) {
            const float od = __shfl_xor(bd, off, 64);
            const int   ov = __shfl_xor(bv, off, 64);
            if (od < bd || (od == bd && ov < bv)) { bd = od; bv = ov; }
        }
        if (lane == 0) {
            tokens[row] = (float)bv;
            atomicAdd(&cnt[bv], 1.0f);
        }
        const float4 c4 = *(const float4*)(cb + (size_t)bv * EMB + lane * 4);
        *(float4*)(zq + (size_t)row * EMB + lane * 4) = c4;
    }
}

// ---------------------------------------------------------------------------
// Full-scan fallback (expected n ~ 0): LDS-tiled exact scan, atomicMin merge.
// Exits before staging when empty -> near-zero cost in the common case.
// ---------------------------------------------------------------------------
#define RBV 64                       // codes per LDS tile
#define RSPLIT 4                     // row-split blocks per tile
#define NTILE (VOCAB / RBV)          // 128
__global__ __launch_bounds__(256, 2)
void rescue_full_kernel(const int* __restrict__ flagcnt, const int* __restrict__ flist,
                        const float* __restrict__ z, const float* __restrict__ cb,
                        const float* __restrict__ esq,
                        unsigned long long* __restrict__ rkey) {
    const int n = __builtin_amdgcn_readfirstlane(flagcnt[1]);
    if (n == 0) return;

    __shared__ float cs[RBV][EMB];   // 64 KB, swizzled chunks

    const int tile = blockIdx.x >> 2;        // 0..127
    const int rs   = blockIdx.x & 3;         // 0..3
    const int c0   = tile * RBV;
    const int tid  = threadIdx.x;
    const int w    = tid >> 6;
    const int lane = tid & 63;
    const int g    = lane >> 2;              // code group 0..15
    const int s    = lane & 3;               // dim quarter within 16-chunk

    #pragma unroll
    for (int i = 0; i < 16; ++i) {
        const int code = i * 4 + w;
        const float4 v = *(const float4*)(cb + (size_t)(c0 + code) * EMB + lane * 4);
        *(float4*)&cs[code][(lane ^ (code & 7)) * 4] = v;
    }
    __syncthreads();

    const int nq = (n + 3) >> 2;
    const int q0 = (rs << 2) | w;
    if (q0 >= nq) return;                    // after barrier; wave-uniform

    float ev[4];
    #pragma unroll
    for (int gs = 0; gs < 4; ++gs) ev[gs] = esq[c0 + gs * 16 + g];

    for (int q = q0; q < nq; q += 16) {
        int rows[4];
        #pragma unroll
        for (int r = 0; r < 4; ++r) {
            const int fi = q * 4 + r;
            rows[r] = __builtin_amdgcn_readfirstlane(flist[fi < n ? fi : 0]);
        }

        float p[4][4];                        // [gs][row]
        #pragma unroll
        for (int gs = 0; gs < 4; ++gs)
            #pragma unroll
            for (int r = 0; r < 4; ++r) p[gs][r] = 0.0f;

        #pragma unroll
        for (int kb = 0; kb < 4; ++kb) {
            #pragma unroll
            for (int kk = 0; kk < 4; ++kk) {
                const int dbase = (kb * 4 + kk) * 16 + s * 4;
                float4 zv[4];
                #pragma unroll
                for (int r = 0; r < 4; ++r)
                    zv[r] = *(const float4*)(z + (size_t)rows[r] * EMB + dbase);
                const int dq = (kb * 4 + kk) * 4 + s;
                #pragma unroll
                for (int gs = 0; gs < 4; ++gs) {
                    const int code = gs * 16 + g;
                    const float4 c4 = *(const float4*)&cs[code][(dq ^ (code & 7)) * 4];
                    #pragma unroll
                    for (int r = 0; r < 4; ++r)
                        p[gs][r] += zv[r].x * c4.x + zv[r].y * c4.y
                                  + zv[r].z * c4.z + zv[r].w * c4.w;
                }
            }
        }

        #pragma unroll
        for (int gs = 0; gs < 4; ++gs)
            #pragma unroll
            for (int r = 0; r < 4; ++r) {
                float t = p[gs][r];
                t += __shfl_xor(t, 1, 64);
                t += __shfl_xor(t, 2, 64);
                p[gs][r] = t;
            }

        #pragma unroll
        for (int r = 0; r < 4; ++r) {
            float bd = INFINITY; int bv = 0;
            #pragma unroll
            for (int gs = 0; gs < 4; ++gs) {
                const float d = ev[gs] - 2.0f * p[gs][r];
                const int v = c0 + gs * 16 + g;
                if (d < bd) { bd = d; bv = v; }
            }
            #pragma unroll
            for (int off = 4; off < 64; off <<= 1) {
                const float od = __shfl_xor(bd, off, 64);
                const int   ov = __shfl_xor(bv, off, 64);
                if (od < bd || (od == bd && ov < bv)) { bd = od; bv = ov; }
            }
            if (lane == 0 && q * 4 + r < n) {
                unsigned int u = __float_as_uint(bd);
                u = (u & 0x80000000u) ? ~u : (u | 0x80000000u);
                atomicMin(rkey + rows[r], ((unsigned long long)u << 32) | (unsigned int)bv);
            }
        }
    }
}

// ---------------------------------------------------------------------------
// Full-scan writer: separate dispatch (kernel boundary = visibility ordering).
// ---------------------------------------------------------------------------
__global__ void rescue_write_kernel(const int* __restrict__ flagcnt,
                                    const int* __restrict__ flist,
                                    const unsigned long long* __restrict__ rkey,
                                    const float* __restrict__ cb,
                                    float* __restrict__ tokens, float* __restrict__ zq,
                                    float* __restrict__ cnt) {
    const int w    = threadIdx.x >> 6;
    const int lane = threadIdx.x & 63;
    const int n = flagcnt[1];
    for (int f = blockIdx.x * 4 + w; f < n; f += gridDim.x * 4) {
        const int row = flist[f];
        const int v = (int)(unsigned int)(rkey[row] & 0xFFFFFFFFull);
        if (lane == 0) {
            tokens[row] = (float)v;
            atomicAdd(&cnt[v], 1.0f);
        }
        const float4 c4 = *(const float4*)(cb + (size_t)v * EMB + lane * 4);
        *(float4*)(zq + (size_t)row * EMB + lane * 4) = c4;
    }
}

// ===========================================================================
// Fallback (round-3 fp32 path) if ws is too small.
// ===========================================================================
__global__ void esq_kernel(const float* __restrict__ cb, float* __restrict__ esq) {
    const int wave = threadIdx.x >> 6;
    const int lane = threadIdx.x & 63;
    const int row  = blockIdx.x * 4 + wave;
    const float4 v = *(const float4*)(cb + (size_t)row * EMB + lane * 4);
    float s = v.x * v.x + v.y * v.y + v.z * v.z + v.w * v.w;
    #pragma unroll
    for (int off = 32; off > 0; off >>= 1) s += __shfl_down(s, off, 64);
    if (lane == 0) esq[row] = s;
}

#define FLSTR 36
__global__ __launch_bounds__(256, 2)
void fb_dist_kernel(const float* __restrict__ z, const float* __restrict__ cb,
                    const float* __restrict__ esq,
                    float* __restrict__ pdist, int* __restrict__ pidx) {
    __shared__ float zs[BM][FLSTR];
    __shared__ float es[BV][FLSTR];
    __shared__ float rdist[16][16];
    __shared__ int   ridx [16][16];
    const int row0 = blockIdx.x * BM, vbase = blockIdx.y * VRANGE;
    const int tid = threadIdx.x, wave = tid >> 6, lane = tid & 63;
    const int wly = (lane >> 3) & 7, wlx = lane & 7;
    const int wbase = (wave >> 1) * 64, cbase = (wave & 1) * 64;
    const int arow = wbase + wly, bcol = cbase + wlx;
    const int rowSlot = (wave >> 1) * 8 + wly, colSlot = (wave & 1) * 8 + wlx;
    const int sc4 = tid & 7, sr0 = tid >> 3;
    float best[8]; int bidx[8];
    #pragma unroll
    for (int i = 0; i < 8; ++i) { best[i] = INFINITY; bidx[i] = 0; }
    for (int vt = 0; vt < NVT; ++vt) {
        const int v0 = vbase + vt * BV;
        float acc[8][8];
        #pragma unroll
        for (int i = 0; i < 8; ++i)
            #pragma unroll
            for (int j = 0; j < 8; ++j) acc[i][j] = 0.0f;
        #pragma unroll 1
        for (int kt = 0; kt < EMB / 32; ++kt) {
            #pragma unroll
            for (int t = 0; t < 4; ++t) {
                const int r = sr0 + 32 * t;
                *(float4*)&zs[r][sc4 * 4] = *(const float4*)(z  + (size_t)(row0 + r) * EMB + kt * 32 + sc4 * 4);
                *(float4*)&es[r][sc4 * 4] = *(const float4*)(cb + (size_t)(v0 + r) * EMB + kt * 32 + sc4 * 4);
            }
            __syncthreads();
            #pragma unroll 1
            for (int k0 = 0; k0 < 8; ++k0) {
                const int kk = k0 * 4;
                float a[8][4];
                #pragma unroll
                for (int i = 0; i < 8; ++i) {
                    const float4 a4 = *(const float4*)&zs[arow + 8 * i][kk];
                    a[i][0] = a4.x; a[i][1] = a4.y; a[i][2] = a4.z; a[i][3] = a4.w;
                }
                #pragma unroll
                for (int j = 0; j < 8; ++j) {
                    const float4 b4 = *(const float4*)&es[bcol + 8 * j][kk];
                    #pragma unroll
                    for (int i = 0; i < 8; ++i) {
                        acc[i][j] += a[i][0] * b4.x; acc[i][j] += a[i][1] * b4.y;
                        acc[i][j] += a[i][2] * b4.z; acc[i][j] += a[i][3] * b4.w;
                    }
                }
            }
            __syncthreads();
        }
        #pragma unroll
        for (int j = 0; j < 8; ++j) {
            const int v = v0 + bcol + 8 * j;
            const float evv = esq[v];
            #pragma unroll
            for (int i = 0; i < 8; ++i) {
                const float d = evv - 2.0f * acc[i][j];
                if (d < best[i]) { best[i] = d; bidx[i] = v; }
            }
        }
    }
    for (int i = 0; i < 8; ++i) {
        rdist[rowSlot][colSlot] = best[i];
        ridx [rowSlot][colSlot] = bidx[i];
        __syncthreads();
        if (colSlot == 0) {
            float bd = rdist[rowSlot][0]; int bi = ridx[rowSlot][0];
            #pragma unroll
            for (int t = 1; t < 16; ++t) {
                const float d = rdist[rowSlot][t]; const int ii = ridx[rowSlot][t];
                if (d < bd || (d == bd && ii < bi)) { bd = d; bi = ii; }
            }
            const int row = row0 + wbase + 8 * i + wly;
            pdist[(size_t)blockIdx.y * N_ROWS + row] = bd;
            pidx [(size_t)blockIdx.y * N_ROWS + row] = bi;
        }
        __syncthreads();
    }
}

__global__ void fb_combine_kernel(const float* __restrict__ pdist, const int* __restrict__ pidx,
                                  const float* __restrict__ cb,
                                  float* __restrict__ tokens, float* __restrict__ zq,
                                  float* __restrict__ cnt) {
    const int wave = threadIdx.x >> 6, lane = threadIdx.x & 63;
    const int row = blockIdx.x * 4 + wave;
    float bd = INFINITY; int bi = 0;
    #pragma unroll
    for (int s = 0; s < VSPLIT; ++s) {
        const float d = pdist[(size_t)s * N_ROWS + row];
        const int ii  = pidx [(size_t)s * N_ROWS + row];
        if (d < bd || (d == bd && ii < bi)) { bd = d; bi = ii; }
    }
    if (lane == 0) { tokens[row] = (float)bi; atomicAdd(&cnt[bi], 1.0f); }
    const float4 v = *(const float4*)(cb + (size_t)bi * EMB + lane * 4);
    *(float4*)(zq + (size_t)row * EMB + lane * 4) = v;
}

// ---------------------------------------------------------------------------
// d_out: [0,N) tokens | [N, N+N*EMB) zq | +VOCAB ref_count
// ws: zh | ch | esq | pd1|pd2|pd3|pi1|pi2 | rkey | counters | clist | flist
// 6 dispatches: prep -> mfma_dist -> combine -> rescue_cand -> rescue_full
//               -> rescue_write
// ---------------------------------------------------------------------------
extern "C" void kernel_launch(void* const* d_in, const int* in_sizes, int n_in,
                              void* d_out, int out_size, void* d_ws, size_t ws_size,
                              hipStream_t stream) {
    const float* z  = (const float*)d_in[0];
    const float* cb = (const float*)d_in[1];

    float* out    = (float*)d_out;
    float* tokens = out;
    float* zq     = out + N_ROWS;
    float* cnt    = out + N_ROWS + (size_t)N_ROWS * EMB;

    const size_t ZE = (size_t)N_ROWS * EMB, CE = (size_t)VOCAB * EMB, P = (size_t)VSPLIT * N_ROWS;
    const size_t NEED = (ZE + CE) * sizeof(_Float16) + VOCAB * 4
                      + 5 * P * 4 + (size_t)N_ROWS * 8 + 256 + 2 * (size_t)N_ROWS * 4;

    if (ws_size >= NEED) {
        char* p = (char*)d_ws;
        _Float16* zh = (_Float16*)p;            p += ZE * 2;
        _Float16* ch = (_Float16*)p;            p += CE * 2;
        float* esq   = (float*)p;               p += VOCAB * 4;
        float* pd1   = (float*)p;               p += P * 4;
        float* pd2   = (float*)p;               p += P * 4;
        float* pd3   = (float*)p;               p += P * 4;
        int*   pi1   = (int*)p;                 p += P * 4;
        int*   pi2   = (int*)p;                 p += P * 4;
        unsigned long long* rkey = (unsigned long long*)p;  p += (size_t)N_ROWS * 8;
        int*   flagcnt = (int*)p;               p += 256;
        int*   clist = (int*)p;                 p += (size_t)N_ROWS * 4;
        int*   flist = (int*)p;

        prep_kernel<<<VOCAB / 4 + (int)(ZE / 4 / 256), 256, 0, stream>>>(
            z, cb, zh, ch, esq, cnt, rkey, flagcnt);
        mfma_dist_kernel<<<dim3(N_ROWS / BM, VSPLIT), 256, 0, stream>>>(
            zh, ch, esq, pd1, pd2, pd3, pi1, pi2);
        combine_kernel<<<N_ROWS / 4, 256, 0, stream>>>(
            pd1, pd2, pd3, pi1, cb, tokens, zq, cnt, flagcnt, clist, flist);
        rescue_cand_kernel<<<512, 256, 0, stream>>>(
            flagcnt, clist, z, cb, esq, pi1, pi2, tokens, zq, cnt);
        rescue_full_kernel<<<NTILE * RSPLIT, 256, 0, stream>>>(
            flagcnt, flist, z, cb, esq, rkey);
        rescue_write_kernel<<<32, 256, 0, stream>>>(
            flagcnt, flist, rkey, cb, tokens, zq, cnt);
    } else {
        float* esq   = (float*)d_ws;
        float* pdist = esq + VOCAB;
        int*   pidx  = (int*)(pdist + P);
        hipMemsetAsync(cnt, 0, VOCAB * sizeof(float), stream);
        esq_kernel<<<VOCAB / 4, 256, 0, stream>>>(cb, esq);
        fb_dist_kernel<<<dim3(N_ROWS / BM, VSPLIT), 256, 0, stream>>>(z, cb, esq, pdist, pidx);
        fb_combine_kernel<<<N_ROWS / 4, 256, 0, stream>>>(pdist, pidx, cb, tokens, zq, cnt);
    }
}